// Round 15
// baseline (68.183 us; speedup 1.0000x reference)
//
#include <hip/hip_runtime.h>

// SimpleRNN: B=8192, T=1024, H=8.
// v8 = v7 (asm fmac_dpp step, r-state, hazard nops) with HALF-WAVES:
// 4 batches per wave (lanes 0-31 active), 2048 waves = 2 waves/SIMD.
// Theory: ~5.5cyc/instr cadence is PER-WAVE; two waves/SIMD interleave in the
// VALU pipe -> fill dependency stalls. Per-SIMD floor 2x13x2=52 cyc per 8 batches
// vs 110 measured at 1 wave/SIMD. Predict 47.5 -> 26-34 us.

#define T_LEN 1024
#define DPP_XOR1 0xB1   // quad_perm(1,0,3,2)
#define DPP_XOR2 0x4E   // quad_perm(2,3,0,1)
#define DPP_XOR7 0x141  // row_half_mirror
#define K_2LN2 2.8853900817779268f

template <int CTRL>
__device__ __forceinline__ float fdpp(float v) {
    int i = __builtin_bit_cast(int, v);
    int r = __builtin_amdgcn_mov_dpp(i, CTRL, 0xF, 0xF, true);
    return __builtin_bit_cast(float, r);
}

__device__ __forceinline__ float fast_sigmoid(float z) {
    float e = __builtin_amdgcn_exp2f(z * -1.4426950408889634f);
    return __builtin_amdgcn_rcpf(1.0f + e);
}

// Hazard spacing (within-wave, independent of co-resident waves):
//  exp2 -> s_nop 1 -> add ; rcp -> s_nop 1 -> fma ; rcp ->(3+ slots)-> mov_dpp.
#define STEP(PRE)                                                              \
    asm volatile(                                                              \
        "v_fma_f32 %[u], %[r], %[w0], %[p]\n\t"                                \
        "v_mov_b32_dpp %[m7], %[r] row_half_mirror row_mask:0xf bank_mask:0xf\n\t" \
        "v_fmac_f32_dpp %[u], %[r], %[w1] quad_perm:[1,0,3,2] row_mask:0xf bank_mask:0xf\n\t" \
        "v_fmac_f32_dpp %[u], %[r], %[w2] quad_perm:[2,3,0,1] row_mask:0xf bank_mask:0xf\n\t" \
        "v_fmac_f32_dpp %[u], %[r], %[w3] quad_perm:[3,2,1,0] row_mask:0xf bank_mask:0xf\n\t" \
        "v_fmac_f32 %[u], %[m7], %[w7]\n\t"                                    \
        "v_fmac_f32_dpp %[u], %[m7], %[w4] quad_perm:[3,2,1,0] row_mask:0xf bank_mask:0xf\n\t" \
        "v_fmac_f32_dpp %[u], %[m7], %[w5] quad_perm:[2,3,0,1] row_mask:0xf bank_mask:0xf\n\t" \
        "v_fmac_f32_dpp %[u], %[m7], %[w6] quad_perm:[1,0,3,2] row_mask:0xf bank_mask:0xf\n\t" \
        "v_exp_f32 %[e], %[u]\n\t"                                             \
        "s_nop 1\n\t"                                                          \
        "v_add_f32 %[u], 1.0, %[e]\n\t"                                        \
        "v_rcp_f32 %[r], %[u]\n\t"                                             \
        "s_nop 1\n\t"                                                          \
        : [r]"+v"(r), [u]"=&v"(u_t), [e]"=&v"(e_t), [m7]"=&v"(m7_t)            \
        : [p]"v"(PRE), [w0]"v"(wq0), [w1]"v"(wq1), [w2]"v"(wq2),               \
          [w3]"v"(wq3), [w4]"v"(wq4), [w5]"v"(wq5), [w6]"v"(wq6),              \
          [w7]"v"(wq7))

__global__ __launch_bounds__(256) void rnn_oct_asm2_kernel(
    const float* __restrict__ x, const float* __restrict__ W_ih,
    const float* __restrict__ W_hh, const float* __restrict__ b_ih,
    const float* __restrict__ b_hh, const float* __restrict__ W_fc,
    const float* __restrict__ b_fc, float* __restrict__ out, int B)
{
    const int lane = threadIdx.x & 63;
    if (lane >= 32) return;                       // half-wave: 4 batches on lanes 0-31
    const int gw = (blockIdx.x * 256 + threadIdx.x) >> 6;   // global wave id, 0..2047
    const int j = lane & 7;                       // state element
    const int b = gw * 4 + (lane >> 3);           // batch
    if (b >= B) return;

    // wq[m] = -2K * W_hh[j][j^m];  rowsum folds into bias (h = 1-2r)
    float wv0 = W_hh[j * 8 + (j ^ 0)];
    float wv1 = W_hh[j * 8 + (j ^ 1)];
    float wv2 = W_hh[j * 8 + (j ^ 2)];
    float wv3 = W_hh[j * 8 + (j ^ 3)];
    float wv4 = W_hh[j * 8 + (j ^ 4)];
    float wv5 = W_hh[j * 8 + (j ^ 5)];
    float wv6 = W_hh[j * 8 + (j ^ 6)];
    float wv7 = W_hh[j * 8 + (j ^ 7)];
    float rowsum = ((wv0 + wv1) + (wv2 + wv3)) + ((wv4 + wv5) + (wv6 + wv7));
    const float wq0 = -2.0f * K_2LN2 * wv0;
    const float wq1 = -2.0f * K_2LN2 * wv1;
    const float wq2 = -2.0f * K_2LN2 * wv2;
    const float wq3 = -2.0f * K_2LN2 * wv3;
    const float wq4 = -2.0f * K_2LN2 * wv4;
    const float wq5 = -2.0f * K_2LN2 * wv5;
    const float wq6 = -2.0f * K_2LN2 * wv6;
    const float wq7 = -2.0f * K_2LN2 * wv7;
    const float biasp = K_2LN2 * (b_ih[j] + b_hh[j] + rowsum);
    const float wihp  = K_2LN2 * W_ih[j];

    const float wfc = W_fc[j];
    float sw = wfc;                       // 8-lane group sum of W_fc
    sw += fdpp<DPP_XOR1>(sw);
    sw += fdpp<DPP_XOR2>(sw);
    sw += fdpp<DPP_XOR7>(sw);
    const float cfc  = b_fc[0] + sw;      // bfc + sum_j wfc[j]
    const float wfc2 = -2.0f * wfc;

    const float* xb = x + (size_t)b * T_LEN;
    float r = 0.5f;                       // h=0 -> r=0.5
    float u_t, e_t, m7_t;

    // 16-step chunks: extract pre[16], then refill A regs (loads hide under steps).
    float4 A0 = *(const float4*)(xb + 0);
    float4 A1 = *(const float4*)(xb + 4);
    float4 A2 = *(const float4*)(xb + 8);
    float4 A3 = *(const float4*)(xb + 12);

#pragma unroll 1
    for (int t0 = 0; t0 < T_LEN; t0 += 16) {
        float pre[16];
        pre[0]  = __builtin_fmaf(A0.x, wihp, biasp);
        pre[1]  = __builtin_fmaf(A0.y, wihp, biasp);
        pre[2]  = __builtin_fmaf(A0.z, wihp, biasp);
        pre[3]  = __builtin_fmaf(A0.w, wihp, biasp);
        pre[4]  = __builtin_fmaf(A1.x, wihp, biasp);
        pre[5]  = __builtin_fmaf(A1.y, wihp, biasp);
        pre[6]  = __builtin_fmaf(A1.z, wihp, biasp);
        pre[7]  = __builtin_fmaf(A1.w, wihp, biasp);
        pre[8]  = __builtin_fmaf(A2.x, wihp, biasp);
        pre[9]  = __builtin_fmaf(A2.y, wihp, biasp);
        pre[10] = __builtin_fmaf(A2.z, wihp, biasp);
        pre[11] = __builtin_fmaf(A2.w, wihp, biasp);
        pre[12] = __builtin_fmaf(A3.x, wihp, biasp);
        pre[13] = __builtin_fmaf(A3.y, wihp, biasp);
        pre[14] = __builtin_fmaf(A3.z, wihp, biasp);
        pre[15] = __builtin_fmaf(A3.w, wihp, biasp);

        if (t0 + 16 < T_LEN) {            // refill consumed regs
            A0 = *(const float4*)(xb + t0 + 16);
            A1 = *(const float4*)(xb + t0 + 20);
            A2 = *(const float4*)(xb + t0 + 24);
            A3 = *(const float4*)(xb + t0 + 28);
        }

#pragma unroll
        for (int i = 0; i < 16; ++i)
            STEP(pre[i]);
    }

    // out[b] = sigmoid(cfc + sum_j wfc2[j]*r[j])
    float sv = r * wfc2;
    sv += fdpp<DPP_XOR1>(sv);
    sv += fdpp<DPP_XOR2>(sv);
    sv += fdpp<DPP_XOR7>(sv);
    if (j == 0) out[b] = fast_sigmoid(sv + cfc);
}

extern "C" void kernel_launch(void* const* d_in, const int* in_sizes, int n_in,
                              void* d_out, int out_size, void* d_ws, size_t ws_size,
                              hipStream_t stream) {
    const float* x    = (const float*)d_in[0];
    const float* W_ih = (const float*)d_in[1];
    const float* W_hh = (const float*)d_in[2];
    const float* b_ih = (const float*)d_in[3];
    const float* b_hh = (const float*)d_in[4];
    const float* W_fc = (const float*)d_in[5];
    const float* b_fc = (const float*)d_in[6];
    float* out = (float*)d_out;

    const int B = in_sizes[0] / T_LEN;     // 8192
    // 4 batches per wave (lanes 0-31), 2048 waves = 2/SIMD chip-wide
    const int waves = (B + 3) / 4;
    const int grid = (waves * 64 + 255) / 256;   // 512 blocks of 256
    rnn_oct_asm2_kernel<<<grid, 256, 0, stream>>>(x, W_ih, W_hh, b_ih, b_hh, W_fc, b_fc, out, B);
}

// Round 16
// 43.898 us; speedup vs baseline: 1.5532x; 1.5532x over previous
//
#include <hip/hip_runtime.h>

// SimpleRNN: B=8192, T=1024, H=8.
// v9 = v7 (1024 full waves, 1/SIMD, asm fmac_dpp step) + last slot shavings:
//  - pre-FMA moved into the exp2 hazard shadow (spacing stays 2 wait states)
//  - header = loads only; 32-step A/B double-buffered chunks
//  - ring-4 pre[] with static indices (k&3 / (k+2)&3), no carry movs
// Model (v1-v8 fit): wall/step = 5.5*slots + 16*trans per wave at 1 wave/SIMD.
// Structural floor ~13 slots + 2 trans = ~103 cyc -> 44us. v7 measured 110.6 (47.5us).

#define T_LEN 1024
#define DPP_XOR1 0xB1   // quad_perm(1,0,3,2)
#define DPP_XOR2 0x4E   // quad_perm(2,3,0,1)
#define DPP_XOR7 0x141  // row_half_mirror
#define K_2LN2 2.8853900817779268f

template <int CTRL>
__device__ __forceinline__ float fdpp(float v) {
    int i = __builtin_bit_cast(int, v);
    int r = __builtin_amdgcn_mov_dpp(i, CTRL, 0xF, 0xF, true);
    return __builtin_bit_cast(float, r);
}

__device__ __forceinline__ float fast_sigmoid(float z) {
    float e = __builtin_amdgcn_exp2f(z * -1.4426950408889634f);
    return __builtin_amdgcn_rcpf(1.0f + e);
}

// Hazard spacing (identical margins to the proven v7):
//  exp2 -> [preFMA, s_nop0] (2 states) -> add reads e
//  rcp  -> [s_nop 1] (2 states) -> next step's fma reads r
//  rcp  -> 3+ slots -> mov_dpp DPP-reads r (needs 2)
//  preFMA writes pd; its single read is 2 steps (~30 slots) later.
#define STEP(PUSE, PDEF, X)                                                    \
    asm volatile(                                                              \
        "v_fma_f32 %[u], %[r], %[w0], %[pu]\n\t"                               \
        "v_mov_b32_dpp %[m7], %[r] row_half_mirror row_mask:0xf bank_mask:0xf\n\t" \
        "v_fmac_f32_dpp %[u], %[r], %[w1] quad_perm:[1,0,3,2] row_mask:0xf bank_mask:0xf\n\t" \
        "v_fmac_f32_dpp %[u], %[r], %[w2] quad_perm:[2,3,0,1] row_mask:0xf bank_mask:0xf\n\t" \
        "v_fmac_f32_dpp %[u], %[r], %[w3] quad_perm:[3,2,1,0] row_mask:0xf bank_mask:0xf\n\t" \
        "v_fmac_f32 %[u], %[m7], %[w7]\n\t"                                    \
        "v_fmac_f32_dpp %[u], %[m7], %[w4] quad_perm:[3,2,1,0] row_mask:0xf bank_mask:0xf\n\t" \
        "v_fmac_f32_dpp %[u], %[m7], %[w5] quad_perm:[2,3,0,1] row_mask:0xf bank_mask:0xf\n\t" \
        "v_fmac_f32_dpp %[u], %[m7], %[w6] quad_perm:[1,0,3,2] row_mask:0xf bank_mask:0xf\n\t" \
        "v_exp_f32 %[e], %[u]\n\t"                                             \
        "v_fma_f32 %[pd], %[x], %[wih], %[bs]\n\t"                             \
        "s_nop 0\n\t"                                                          \
        "v_add_f32 %[u], 1.0, %[e]\n\t"                                        \
        "v_rcp_f32 %[r], %[u]\n\t"                                             \
        "s_nop 1\n\t"                                                          \
        : [r]"+v"(r), [u]"=&v"(u_t), [e]"=&v"(e_t), [m7]"=&v"(m7_t),           \
          [pd]"=&v"(PDEF)                                                      \
        : [pu]"v"(PUSE), [x]"v"(X), [wih]"v"(wihp), [bs]"v"(biasp),            \
          [w0]"v"(wq0), [w1]"v"(wq1), [w2]"v"(wq2), [w3]"v"(wq3),              \
          [w4]"v"(wq4), [w5]"v"(wq5), [w6]"v"(wq6), [w7]"v"(wq7))

__global__ __launch_bounds__(256) void rnn_oct_asm3_kernel(
    const float* __restrict__ x, const float* __restrict__ W_ih,
    const float* __restrict__ W_hh, const float* __restrict__ b_ih,
    const float* __restrict__ b_hh, const float* __restrict__ W_fc,
    const float* __restrict__ b_fc, float* __restrict__ out, int B)
{
    const int tid = blockIdx.x * 256 + threadIdx.x;
    const int j = tid & 7;        // state element
    const int b = tid >> 3;       // batch
    if (b >= B) return;

    // wq[m] = -2K * W_hh[j][j^m]; rowsum folds into bias (h = 1-2r, r = rcp(2^u+1))
    float wv0 = W_hh[j * 8 + (j ^ 0)];
    float wv1 = W_hh[j * 8 + (j ^ 1)];
    float wv2 = W_hh[j * 8 + (j ^ 2)];
    float wv3 = W_hh[j * 8 + (j ^ 3)];
    float wv4 = W_hh[j * 8 + (j ^ 4)];
    float wv5 = W_hh[j * 8 + (j ^ 5)];
    float wv6 = W_hh[j * 8 + (j ^ 6)];
    float wv7 = W_hh[j * 8 + (j ^ 7)];
    float rowsum = ((wv0 + wv1) + (wv2 + wv3)) + ((wv4 + wv5) + (wv6 + wv7));
    const float wq0 = -2.0f * K_2LN2 * wv0;
    const float wq1 = -2.0f * K_2LN2 * wv1;
    const float wq2 = -2.0f * K_2LN2 * wv2;
    const float wq3 = -2.0f * K_2LN2 * wv3;
    const float wq4 = -2.0f * K_2LN2 * wv4;
    const float wq5 = -2.0f * K_2LN2 * wv5;
    const float wq6 = -2.0f * K_2LN2 * wv6;
    const float wq7 = -2.0f * K_2LN2 * wv7;
    const float biasp = K_2LN2 * (b_ih[j] + b_hh[j] + rowsum);
    const float wihp  = K_2LN2 * W_ih[j];

    const float wfc = W_fc[j];
    float sw = wfc;                       // 8-lane group sum of W_fc
    sw += fdpp<DPP_XOR1>(sw);
    sw += fdpp<DPP_XOR2>(sw);
    sw += fdpp<DPP_XOR7>(sw);
    const float cfc  = b_fc[0] + sw;      // bfc + sum_j wfc[j]
    const float wfc2 = -2.0f * wfc;

    const float* xb = x + (size_t)b * T_LEN;
    float r = 0.5f;                       // h=0 -> r=0.5
    float u_t, e_t, m7_t;

    // 32-step chunks: A = x[t0..t0+15], B = x[t0+16..t0+31]
    float4 A0 = *(const float4*)(xb + 0);
    float4 A1 = *(const float4*)(xb + 4);
    float4 A2 = *(const float4*)(xb + 8);
    float4 A3 = *(const float4*)(xb + 12);
    float4 B0 = *(const float4*)(xb + 16);
    float4 B1 = *(const float4*)(xb + 20);
    float4 B2 = *(const float4*)(xb + 24);
    float4 B3 = *(const float4*)(xb + 28);

    // ring-4 pre buffer; step k uses pre[k&3], defines pre[(k+2)&3] (all static)
    float pre[4];
    pre[0] = __builtin_fmaf(A0.x, wihp, biasp);
    pre[1] = __builtin_fmaf(A0.y, wihp, biasp);

#pragma unroll 1
    for (int t0 = 0; t0 < T_LEN; t0 += 32) {
        // first half: consumes A; X tail (k=14,15) from B0
        STEP(pre[0], pre[2], A0.z);
        STEP(pre[1], pre[3], A0.w);
        STEP(pre[2], pre[0], A1.x);
        STEP(pre[3], pre[1], A1.y);
        STEP(pre[0], pre[2], A1.z);
        STEP(pre[1], pre[3], A1.w);
        STEP(pre[2], pre[0], A2.x);
        STEP(pre[3], pre[1], A2.y);
        STEP(pre[0], pre[2], A2.z);
        STEP(pre[1], pre[3], A2.w);
        STEP(pre[2], pre[0], A3.x);
        STEP(pre[3], pre[1], A3.y);
        STEP(pre[0], pre[2], A3.z);
        STEP(pre[1], pre[3], A3.w);
        STEP(pre[2], pre[0], B0.x);
        STEP(pre[3], pre[1], B0.y);

        // refill A <- x[t0+32 .. t0+47] (A dead; first use of new A0 at k=30)
        {
            int offA = t0 + 32;
            if (offA > T_LEN - 16) offA = 0;      // clamped dummy on last iter
            const float4* pA = (const float4*)(xb + offA);
            A0 = pA[0]; A1 = pA[1]; A2 = pA[2]; A3 = pA[3];
        }

        // second half: consumes B; X tail (k=30,31) from new A0
        STEP(pre[0], pre[2], B0.z);
        STEP(pre[1], pre[3], B0.w);
        STEP(pre[2], pre[0], B1.x);
        STEP(pre[3], pre[1], B1.y);
        STEP(pre[0], pre[2], B1.z);
        STEP(pre[1], pre[3], B1.w);
        STEP(pre[2], pre[0], B2.x);
        STEP(pre[3], pre[1], B2.y);
        STEP(pre[0], pre[2], B2.z);
        STEP(pre[1], pre[3], B2.w);
        STEP(pre[2], pre[0], B3.x);
        STEP(pre[3], pre[1], B3.y);
        STEP(pre[0], pre[2], B3.z);
        STEP(pre[1], pre[3], B3.w);
        STEP(pre[2], pre[0], A0.x);               // new A
        STEP(pre[3], pre[1], A0.y);

        // refill B <- x[t0+48 .. t0+63] (next use 16 steps away)
        {
            int offB = t0 + 48;
            if (offB > T_LEN - 16) offB = 0;      // clamped dummy near the end
            const float4* pB = (const float4*)(xb + offB);
            B0 = pB[0]; B1 = pB[1]; B2 = pB[2]; B3 = pB[3];
        }
    }

    // out[b] = sigmoid(cfc + sum_j wfc2[j]*r[j])
    float sv = r * wfc2;
    sv += fdpp<DPP_XOR1>(sv);
    sv += fdpp<DPP_XOR2>(sv);
    sv += fdpp<DPP_XOR7>(sv);
    if (j == 0) out[b] = fast_sigmoid(sv + cfc);
}

extern "C" void kernel_launch(void* const* d_in, const int* in_sizes, int n_in,
                              void* d_out, int out_size, void* d_ws, size_t ws_size,
                              hipStream_t stream) {
    const float* x    = (const float*)d_in[0];
    const float* W_ih = (const float*)d_in[1];
    const float* W_hh = (const float*)d_in[2];
    const float* b_ih = (const float*)d_in[3];
    const float* b_hh = (const float*)d_in[4];
    const float* W_fc = (const float*)d_in[5];
    const float* b_fc = (const float*)d_in[6];
    float* out = (float*)d_out;

    const int B = in_sizes[0] / T_LEN;     // 8192
    const int threads = B * 8;             // 65536 threads = 1024 full waves = 1/SIMD
    const int grid = threads / 256;
    rnn_oct_asm3_kernel<<<grid, 256, 0, stream>>>(x, W_ih, W_hh, b_ih, b_hh, W_fc, b_fc, out, B);
}